// Round 13
// baseline (191.993 us; speedup 1.0000x reference)
//
#include <hip/hip_runtime.h>
#include <math.h>

#define NB 4
#define NH 512
#define NW 512
#define NC 19
#define NPIX (NB*NH*NW)
#define TS 16
#define NLAD 128
#define INF6 1.0e6f
#define MAXDIS 1.0e5f
#define NWRD 16          // 512 rows / 32 bits
#define NREP 8           // histogram replicas
#define HSTRIDE 132      // padded per-replica stride (129 bins)
#define NSEG 128         // compaction segments
#define SEGCAP 512       // entries per segment (expected max ~250)
#define NDCB (NSEG*SEGCAP*8/256)      // dirce blocks = 2048
#define NZERO (NREP*HSTRIDE + NSEG)   // hist + cnts words zeroed by bound blk 0

// ---------------------------------------------------------------------------
// Stage 1a: boundary bitmasks. One thread per (b, word, column).
// Block 0 zeroes hist+cnts (stream order guards all consumers).
// ---------------------------------------------------------------------------
__global__ __launch_bounds__(64) void bound_kernel(const int* __restrict__ tgt,
                                                   unsigned int* __restrict__ maskw,
                                                   unsigned int* __restrict__ zbuf) {
    int cidx = blockIdx.x * 64 + threadIdx.x;           // [b][w][j], 32768 total
    if (blockIdx.x == 0) {
        for (int k = threadIdx.x; k < NZERO; k += 64) zbuf[k] = 0u;
    }
    int j = cidx & (NW - 1);
    int w = (cidx >> 9) & (NWRD - 1);
    int b = cidx >> 13;
    const int* t = tgt + (size_t)b * NH * NW;
    unsigned int mask = 0u;
    int i0 = w * 32;
    int cur = t[(size_t)i0 * NW + j];
    for (int k = 0; k < 32; ++k) {
        int i = i0 + k;
        int nxt = (i + 1 < NH) ? t[(size_t)(i + 1) * NW + j] : cur;
        bool bnd = (cur == 255);
        if (i + 1 < NH && nxt != cur) bnd = true;
        if (j + 1 < NW && t[(size_t)i * NW + j + 1] != cur) bnd = true;
        if (bnd) mask |= (1u << k);
        cur = nxt;
    }
    maskw[cidx] = mask;
}

// ---------------------------------------------------------------------------
// Stage 1b+2 fused: block per row; batch mask set in LDS; nearest-set-bit ->
// G^2 -> row min-plus transform -> final dist.
// ---------------------------------------------------------------------------
__global__ __launch_bounds__(512) void vdistrow_kernel(const unsigned int* __restrict__ maskw,
                                                       float* __restrict__ dist) {
    __shared__ unsigned int smw[NWRD][NW];   // 32 KB: all masks of this batch
    __shared__ float s[NW];
    __shared__ unsigned int anyw[8];
    const int tid = threadIdx.x;             // = column j
    const int row = blockIdx.x;              // b*NH + i
    const int b = row >> 9;
    const int i = row & (NH - 1);
    const unsigned int* mcol = maskw + (size_t)b * NWRD * NW;
    unsigned int acc = 0u;
#pragma unroll
    for (int w = 0; w < NWRD; ++w) {
        unsigned int v = mcol[w * NW + tid];
        smw[w][tid] = v;
        acc |= v;
    }
    unsigned long long bal = __ballot(acc != 0u);
    if ((tid & 63) == 0) anyw[tid >> 6] = (bal != 0ull) ? 1u : 0u;

    const int wi = i >> 5, bi = i & 31;
    int down = 1 << 20;
    unsigned int m = smw[wi][tid] & ((2u << bi) - 1u);   // bits 0..bi
    if (m) down = bi - (31 - __clz(m));
    else {
        for (int w = wi - 1; w >= 0; --w) {
            unsigned int mm = smw[w][tid];
            if (mm) { down = bi + 32 * (wi - w) - (31 - __clz(mm)); break; }
        }
    }
    int up = 1 << 20;
    unsigned int mu = smw[wi][tid] & ~((1u << bi) - 1u); // bits bi..31
    if (mu) up = (__ffs(mu) - 1) - bi;
    else {
        for (int w = wi + 1; w < NWRD; ++w) {
            unsigned int mm = smw[w][tid];
            if (mm) { up = 32 * (w - wi) + (__ffs(mm) - 1) - bi; break; }
        }
    }
    int gi = min(down, up);
    float G = (gi >= (1 << 20)) ? INF6 : (float)gi;
    s[tid] = G * G;
    __syncthreads();
    bool has = (anyw[0] | anyw[1] | anyw[2] | anyw[3] |
                anyw[4] | anyw[5] | anyw[6] | anyw[7]) != 0u;
    float best = s[tid];
    for (int r = 1; r < NW; ++r) {
        float rr = (float)(r * r);
        if (rr >= best) break;
        int jl = tid - r, jr = tid + r;
        if (jl >= 0) best = fminf(best, s[jl] + rr);
        if (jr < NW) best = fminf(best, s[jr] + rr);
    }
    dist[(size_t)row * NW + tid] = has ? fmaxf(sqrtf(best) - 1.f, 0.f) : 0.f;
}

// ---------------------------------------------------------------------------
// Stage 3a: LSE map, 8 lanes per pixel. Lane d covers channels {d, d+8,
// d+16|d<3}; group loads are contiguous 76B runs (coalesced), reductions via
// width-8 shuffles. Minimal LDS/VGPR -> full occupancy, HBM-stream.
// ---------------------------------------------------------------------------
__global__ __launch_bounds__(256) void lse8_kernel(const float* __restrict__ logits,
                                                   float* __restrict__ lsem) {
    const int t = blockIdx.x * 256 + threadIdx.x;
    const int p = t >> 3, d = t & 7;
    const float* base = logits + (size_t)p * NC;
    const bool h3 = (d < 3);
    float v0 = base[d];
    float v1 = base[d + 8];
    float v2 = h3 ? base[d + 16] : v0;
    float mx = fmaxf(fmaxf(v0, v1), v2);
#pragma unroll
    for (int o = 4; o > 0; o >>= 1) mx = fmaxf(mx, __shfl_xor(mx, o, 8));
    float se = expf(v0 - mx) + expf(v1 - mx) + (h3 ? expf(v2 - mx) : 0.f);
#pragma unroll
    for (int o = 4; o > 0; o >>= 1) se += __shfl_xor(se, o, 8);
    if (d == 0) lsem[p] = mx + logf(se);
}

// ---------------------------------------------------------------------------
// Stage 3b: kl map + fused 8-replica histogram, 8 lanes per pixel. p_c from
// the center distribution; dotr/dotd against right/down neighbors; three
// width-8 shuffle reductions. Logits are L3-resident after lse8.
// ---------------------------------------------------------------------------
__global__ __launch_bounds__(256) void kl8_kernel(const float* __restrict__ logits,
                                                  const float* __restrict__ lsem,
                                                  float* __restrict__ klb,
                                                  unsigned int* __restrict__ hist) {
    __shared__ float lad[NLAD];
    __shared__ unsigned int lh[NLAD + 1];
    const int tid = threadIdx.x;
    if (tid == 0) {
        float e = 1e-5f;
        for (int k = 0; k < NLAD; ++k) { lad[k] = e; e *= 1.2f; }
    }
    if (tid < NLAD + 1) lh[tid] = 0u;
    __syncthreads();

    const int t = blockIdx.x * 256 + tid;
    const int p = t >> 3, d = t & 7;
    const int j = p & (NW - 1);
    const int i = (p >> 9) & (NH - 1);
    const bool hasr = (j < NW - 1), hasd = (i < NH - 1);
    const float lse_c = lsem[p];
    const float lse_r = hasr ? lsem[p + 1] : 0.f;
    const float lse_d = hasd ? lsem[p + NW] : 0.f;
    const float* base = logits + (size_t)p * NC;
    const int offr = hasr ? NC : 0;            // clamp keeps reads in-bounds
    const int offd = hasd ? NW * NC : 0;
    const bool h3 = (d < 3);
    float lc0 = base[d], lc1 = base[d + 8], lc2 = h3 ? base[d + 16] : 0.f;
    float lr0 = base[offr + d], lr1 = base[offr + d + 8], lr2 = h3 ? base[offr + d + 16] : 0.f;
    float ld0 = base[offd + d], ld1 = base[offd + d + 8], ld2 = h3 ? base[offd + d + 16] : 0.f;
    float s0 = lc0 - lse_c, s1 = lc1 - lse_c, s2 = lc2 - lse_c;
    float p0 = expf(s0), p1 = expf(s1), p2 = h3 ? expf(s2) : 0.f;
    float negH = p0 * s0 + p1 * s1 + p2 * s2;
    float dotr = p0 * lr0 + p1 * lr1 + p2 * lr2;
    float dotd = p0 * ld0 + p1 * ld1 + p2 * ld2;
#pragma unroll
    for (int o = 4; o > 0; o >>= 1) {
        negH += __shfl_xor(negH, o, 8);
        dotr += __shfl_xor(dotr, o, 8);
        dotd += __shfl_xor(dotd, o, 8);
    }
    if (d == 0) {
        float kl = 0.f;
        if (hasd) kl += negH + lse_d - dotd;
        if (hasr) kl += negH + lse_r - dotr;
        klb[p] = kl;
        int lo = 0, hi = NLAD;
        while (lo < hi) { int mid = (lo + hi) >> 1; if (kl > lad[mid]) lo = mid + 1; else hi = mid; }
        atomicAdd(&lh[lo], 1u);
    }
    __syncthreads();
    if (tid < NLAD + 1 && lh[tid])
        atomicAdd(&hist[(blockIdx.x & (NREP - 1)) * HSTRIDE + tid], lh[tid]);
}

// ---------------------------------------------------------------------------
// Stage 6a: eps (per-block from replica histogram) + validity + compaction.
// ---------------------------------------------------------------------------
__global__ __launch_bounds__(256) void valid_kernel(const float* __restrict__ klb,
                                                    const float* __restrict__ dist,
                                                    const unsigned int* __restrict__ hist,
                                                    unsigned int* __restrict__ cnts,
                                                    unsigned int* __restrict__ list) {
    __shared__ unsigned int tot[NLAD + 1];
    __shared__ float epsS;
    const int tid = threadIdx.x;
    if (tid < NLAD + 1) {
        unsigned int s = 0;
        for (int r = 0; r < NREP; ++r) s += hist[r * HSTRIDE + tid];
        tot[tid] = s;
    }
    __syncthreads();
    if (tid == 0) {
        float lad[NLAD];
        float e = 1e-5f;
        for (int q = 0; q < NLAD; ++q) { lad[q] = e; e *= 1.2f; }
        unsigned int sufs[NLAD + 2];
        sufs[NLAD + 1] = 0u;
        for (int q = NLAD; q >= 0; --q) sufs[q] = sufs[q + 1] + tot[q];
        int K = 0;
        while (K < NLAD - 1 && (float)sufs[K + 1] > 2621.44f) K++;
        epsS = lad[K];
    }
    __syncthreads();
    const float eps = epsS;

    const int b = blockIdx.z;
    const int i = blockIdx.y * TS + (tid >> 4);
    const int j = blockIdx.x * TS + (tid & 15);
    const float* klp = klb + (size_t)b * NH * NW;
    const float* dp = dist + (size_t)b * NH * NW;

    bool pb = false;
    for (int di = -1; di <= 1; ++di) {
        int ii = i + di; if (ii < 0 || ii >= NH) continue;
        for (int dj = -1; dj <= 1; ++dj) {
            int jj = j + dj; if (jj < 0 || jj >= NW) continue;
            if (klp[(size_t)ii * NW + jj] > eps) pb = true;
        }
    }

    const int dxs[9] = {1, -1, 0, 0, -1, 1, -1, 1, 0};
    const int dys[9] = {0, 0, -1, 1, 1, 1, -1, -1, 0};
    float best = MAXDIS; int gidx = 0;
#pragma unroll
    for (int k = 0; k < 9; ++k) {
        int ii = i + dxs[k], jj = j + dys[k];
        float v = (ii >= 0 && ii < NH && jj >= 0 && jj < NW) ? dp[(size_t)ii * NW + jj] : MAXDIS;
        if (k == 0) { best = v; gidx = 0; }
        else if (v < best) { best = v; gidx = k; }
    }
    bool valid = pb && (gidx != 8);

    const int pix = (b * NH + i) * NW + j;
    const int lane = tid & 63;
    unsigned long long mk = __ballot(valid);
    int cnt = __popcll(mk);
    int flatw = (((blockIdx.z * gridDim.y + blockIdx.y) * gridDim.x + blockIdx.x) << 2) | (tid >> 6);
    int seg = flatw & (NSEG - 1);
    unsigned int base = 0u;
    if (lane == 0 && cnt) base = atomicAdd(&cnts[seg], (unsigned int)cnt);
    base = (unsigned int)__shfl((int)base, 0, 64);
    if (valid) {
        unsigned int off = base + (unsigned int)__popcll(mk & ((1ull << lane) - 1ull));
        if (off < SEGCAP)
            list[seg * SEGCAP + off] = (unsigned int)pix | ((unsigned int)gidx << 20);
    }
}

// ---------------------------------------------------------------------------
// Stage 6b: CE over valid pixels, 8 lanes per pixel, PLUS in-block LDS tree
// reduce -> one partial per block (2048 total).
// ---------------------------------------------------------------------------
__global__ __launch_bounds__(256) void dirce_kernel(const float* __restrict__ logits,
                                                    const float* __restrict__ lsem,
                                                    const float* __restrict__ dist,
                                                    const unsigned int* __restrict__ cnts,
                                                    const unsigned int* __restrict__ list,
                                                    float* __restrict__ partials) {
    __shared__ float rs[256];
    const int tid = threadIdx.x;
    const int t = blockIdx.x * 256 + tid;
    const int e = t >> 3;                       // entry slot
    const int d = t & 7;                        // neighbor lane
    const int s = e >> 9;                       // segment (SEGCAP=512)
    const int k = e & (SEGCAP - 1);
    unsigned int cs = cnts[s];
    float myce = 0.f;
    if ((unsigned int)k < min(cs, (unsigned int)SEGCAP)) {
        unsigned int w = list[s * SEGCAP + k];
        const int pix = (int)(w & (NPIX - 1));
        const int gidx = (int)(w >> 20);
        const int j = pix & (NW - 1);
        const int i = (pix >> 9) & (NH - 1);

        const unsigned int DXP = (2u<<0)|(0u<<2)|(1u<<4)|(1u<<6)|(0u<<8)|(2u<<10)|(0u<<12)|(2u<<14);
        const unsigned int DYP = (1u<<0)|(1u<<2)|(0u<<4)|(2u<<6)|(2u<<8)|(2u<<10)|(0u<<12)|(0u<<14);
        const int dx = (int)((DXP >> (2 * d)) & 3u) - 1;
        const int dy = (int)((DYP >> (2 * d)) & 3u) - 1;
        const int ii = i + dx, jj = j + dy;
        const bool inb = (ii >= 0 && ii < NH && jj >= 0 && jj < NW);

        const float lse_c = lsem[pix];
        const float* lcp = logits + (size_t)pix * NC;
        float lc[NC];
        float sumlc = 0.f;
#pragma unroll
        for (int c = 0; c < NC; ++c) { lc[c] = lcp[c]; sumlc += lc[c]; }

        float klm;
        if (inb) {
            const int npix = pix + dx * NW + dy;
            const float lse_n = lsem[npix];
            const float* lnp = logits + (size_t)npix * NC;
            float negH = 0.f, dot = 0.f;
#pragma unroll
            for (int c = 0; c < NC; ++c) {
                float sv = lnp[c] - lse_n;
                float p = expf(sv);
                negH += p * sv;
                dot += p * lc[c];
            }
            klm = negH + lse_c - dot;
        } else {
            klm = -logf(19.f) + lse_c - sumlc / 19.f;
        }

        float m2 = klm;
#pragma unroll
        for (int o = 4; o > 0; o >>= 1) m2 = fmaxf(m2, __shfl_xor(m2, o, 8));
        float ex = expf(klm - m2);
        float s2 = ex;
#pragma unroll
        for (int o = 4; o > 0; o >>= 1) s2 += __shfl_xor(s2, o, 8);
        float lse = m2 + logf(s2);
        float lp = klm - lse;
        float slp = lp;
#pragma unroll
        for (int o = 4; o > 0; o >>= 1) slp += __shfl_xor(slp, o, 8);
        float kg = (d == gidx) ? lp : 0.f;
#pragma unroll
        for (int o = 4; o > 0; o >>= 1) kg += __shfl_xor(kg, o, 8);

        if (d == 0) {
            float ce = -(0.2f / 8.f) * slp - 0.8f * kg;
            float wgt = fminf(dist[pix], 20.f) / 20.f;
            myce = ce * wgt;
        }
    }
    rs[tid] = myce;
    __syncthreads();
    for (int q = 128; q > 0; q >>= 1) {
        if (tid < q) rs[tid] += rs[tid + q];
        __syncthreads();
    }
    if (tid == 0) partials[blockIdx.x] = rs[0];
}

// ---------------------------------------------------------------------------
// Stage 7: reduce 2048 block partials + valid count -> loss.
// ---------------------------------------------------------------------------
__global__ __launch_bounds__(256) void final_kernel(const float* __restrict__ partials,
                                                    const unsigned int* __restrict__ cnts,
                                                    float* __restrict__ out) {
    __shared__ float r[256];
    const int tid = threadIdx.x;
    float s = 0.f;
#pragma unroll
    for (int q = 0; q < NDCB / 256; ++q) s += partials[tid + q * 256];
    r[tid] = s;
    __syncthreads();
    for (int q = 128; q > 0; q >>= 1) {
        if (tid < q) r[tid] += r[tid + q];
        __syncthreads();
    }
    if (tid == 0) {
        unsigned int vf = 0;
        for (int q = 0; q < NSEG; ++q) vf += cnts[q];
        out[0] = r[0] / fmaxf((float)vf, 1.f);
    }
}

extern "C" void kernel_launch(void* const* d_in, const int* in_sizes, int n_in,
                              void* d_out, int out_size, void* d_ws, size_t ws_size,
                              hipStream_t stream) {
    const float* logits = (const float*)d_in[0];
    const int* target = (const int*)d_in[1];
    float* out = (float*)d_out;

    float* fws = (float*)d_ws;
    float* distb = fws;                         // NPIX floats
    float* klb = fws + NPIX;                    // NPIX floats
    float* lsem = fws + 2 * (size_t)NPIX;       // NPIX floats
    unsigned int* hist = (unsigned int*)(fws + 3 * (size_t)NPIX);   // NREP*HSTRIDE
    unsigned int* cnts = hist + NREP * HSTRIDE;                     // NSEG
    unsigned int* list = cnts + NSEG;                               // NSEG*SEGCAP
    float* partials = (float*)(list + NSEG * SEGCAP);               // NDCB
    unsigned int* maskw = (unsigned int*)(partials + NDCB);         // NB*NWRD*NW

    // bound block 0 zeroes hist+cnts; stream order guards all consumers
    bound_kernel<<<NB * NWRD * NW / 64, 64, 0, stream>>>(target, maskw, hist);
    vdistrow_kernel<<<NB * NH, 512, 0, stream>>>(maskw, distb);

    lse8_kernel<<<NPIX * 8 / 256, 256, 0, stream>>>(logits, lsem);
    kl8_kernel<<<NPIX * 8 / 256, 256, 0, stream>>>(logits, lsem, klb, hist);

    dim3 tiles(NW / TS, NH / TS, NB);
    valid_kernel<<<tiles, 256, 0, stream>>>(klb, distb, hist, cnts, list);
    dirce_kernel<<<NDCB, 256, 0, stream>>>(logits, lsem, distb, cnts, list, partials);
    final_kernel<<<1, 256, 0, stream>>>(partials, cnts, out);
}

// Round 14
// 144.956 us; speedup vs baseline: 1.3245x; 1.3245x over previous
//
#include <hip/hip_runtime.h>
#include <math.h>

#define NB 4
#define NH 512
#define NW 512
#define NC 19
#define NPIX (NB*NH*NW)
#define TS 16
#define NLAD 128
#define INF6 1.0e6f
#define MAXDIS 1.0e5f
#define NWRD 16          // 512 rows / 32 bits
#define NREP 8           // histogram replicas
#define HSTRIDE 132      // padded per-replica stride (129 bins)
#define NSEG 128         // compaction segments
#define SEGCAP 512       // entries per segment (expected max ~250)
#define NDCB (NSEG*SEGCAP*8/256)      // dirce blocks = 2048
#define KITER 8          // chunks per klf block
#define NZERO (NREP*HSTRIDE + NSEG)   // hist + cnts words zeroed by bound blk 0

// Compile-time eps ladder: bit-exact IEEE float chain (e = 1e-5f; e *= 1.2f).
struct Lad { float v[NLAD]; };
static constexpr Lad make_lad() {
    Lad t{};
    float e = 1e-5f;
    for (int k = 0; k < NLAD; ++k) { t.v[k] = e; e *= 1.2f; }
    return t;
}
__constant__ Lad LADC = make_lad();

// ---------------------------------------------------------------------------
// Stage 1a: boundary bitmasks. One thread per (b, word, column).
// Block 0 zeroes hist+cnts (stream order guards all consumers).
// ---------------------------------------------------------------------------
__global__ __launch_bounds__(64) void bound_kernel(const int* __restrict__ tgt,
                                                   unsigned int* __restrict__ maskw,
                                                   unsigned int* __restrict__ zbuf) {
    int cidx = blockIdx.x * 64 + threadIdx.x;           // [b][w][j], 32768 total
    if (blockIdx.x == 0) {
        for (int k = threadIdx.x; k < NZERO; k += 64) zbuf[k] = 0u;
    }
    int j = cidx & (NW - 1);
    int w = (cidx >> 9) & (NWRD - 1);
    int b = cidx >> 13;
    const int* t = tgt + (size_t)b * NH * NW;
    unsigned int mask = 0u;
    int i0 = w * 32;
    int cur = t[(size_t)i0 * NW + j];
    for (int k = 0; k < 32; ++k) {
        int i = i0 + k;
        int nxt = (i + 1 < NH) ? t[(size_t)(i + 1) * NW + j] : cur;
        bool bnd = (cur == 255);
        if (i + 1 < NH && nxt != cur) bnd = true;
        if (j + 1 < NW && t[(size_t)i * NW + j + 1] != cur) bnd = true;
        if (bnd) mask |= (1u << k);
        cur = nxt;
    }
    maskw[cidx] = mask;
}

// ---------------------------------------------------------------------------
// Stage 1b+2 fused: block per row; batch mask set in LDS; nearest-set-bit ->
// G^2 -> row min-plus transform -> final dist.
// ---------------------------------------------------------------------------
__global__ __launch_bounds__(512) void vdistrow_kernel(const unsigned int* __restrict__ maskw,
                                                       float* __restrict__ dist) {
    __shared__ unsigned int smw[NWRD][NW];   // 32 KB: all masks of this batch
    __shared__ float s[NW];
    __shared__ unsigned int anyw[8];
    const int tid = threadIdx.x;             // = column j
    const int row = blockIdx.x;              // b*NH + i
    const int b = row >> 9;
    const int i = row & (NH - 1);
    const unsigned int* mcol = maskw + (size_t)b * NWRD * NW;
    unsigned int acc = 0u;
#pragma unroll
    for (int w = 0; w < NWRD; ++w) {
        unsigned int v = mcol[w * NW + tid];
        smw[w][tid] = v;
        acc |= v;
    }
    unsigned long long bal = __ballot(acc != 0u);
    if ((tid & 63) == 0) anyw[tid >> 6] = (bal != 0ull) ? 1u : 0u;

    const int wi = i >> 5, bi = i & 31;
    int down = 1 << 20;
    unsigned int m = smw[wi][tid] & ((2u << bi) - 1u);   // bits 0..bi
    if (m) down = bi - (31 - __clz(m));
    else {
        for (int w = wi - 1; w >= 0; --w) {
            unsigned int mm = smw[w][tid];
            if (mm) { down = bi + 32 * (wi - w) - (31 - __clz(mm)); break; }
        }
    }
    int up = 1 << 20;
    unsigned int mu = smw[wi][tid] & ~((1u << bi) - 1u); // bits bi..31
    if (mu) up = (__ffs(mu) - 1) - bi;
    else {
        for (int w = wi + 1; w < NWRD; ++w) {
            unsigned int mm = smw[w][tid];
            if (mm) { up = 32 * (w - wi) + (__ffs(mm) - 1) - bi; break; }
        }
    }
    int gi = min(down, up);
    float G = (gi >= (1 << 20)) ? INF6 : (float)gi;
    s[tid] = G * G;
    __syncthreads();
    bool has = (anyw[0] | anyw[1] | anyw[2] | anyw[3] |
                anyw[4] | anyw[5] | anyw[6] | anyw[7]) != 0u;
    float best = s[tid];
    for (int r = 1; r < NW; ++r) {
        float rr = (float)(r * r);
        if (rr >= best) break;
        int jl = tid - r, jr = tid + r;
        if (jl >= 0) best = fminf(best, s[jl] + rr);
        if (jr < NW) best = fminf(best, s[jr] + rr);
    }
    dist[(size_t)row * NW + tid] = has ? fmaxf(sqrtf(best) - 1.f, 0.f) : 0.f;
}

// ---------------------------------------------------------------------------
// Stage 3 fused: LSE + kl map + histogram, 8 lanes/pixel, 8 chunks/block.
// Lane d covers channels {d, d+8, d+16|d<3} of center/right/down rows --
// contiguous 76B group runs (coalesced). All three LSEs via width-8 shuffle
// trees (bit-exact with the previous lse8 sequence); lsem written for dirce.
// Ladder from compile-time constant (no per-block serial init); 4096 blocks
// amortize the histogram merge (~8x fewer global atomics than round 13).
// ---------------------------------------------------------------------------
__global__ __launch_bounds__(256) void klf_kernel(const float* __restrict__ logits,
                                                  float* __restrict__ lsem,
                                                  float* __restrict__ klb,
                                                  unsigned int* __restrict__ hist) {
    __shared__ float lad[NLAD];
    __shared__ unsigned int lh[NLAD + 1];
    const int tid = threadIdx.x;
    if (tid < NLAD) lad[tid] = LADC.v[tid];
    if (tid < NLAD + 1) lh[tid] = 0u;
    __syncthreads();

    const int d = tid & 7;
    const bool h3 = (d < 3);
#pragma unroll
    for (int it = 0; it < KITER; ++it) {
        const int p = blockIdx.x * (32 * KITER) + it * 32 + (tid >> 3);
        const int j = p & (NW - 1);
        const int i = (p >> 9) & (NH - 1);
        const bool hasr = (j < NW - 1), hasd = (i < NH - 1);
        const float* base = logits + (size_t)p * NC;
        const int offr = hasr ? NC : 0;        // clamp keeps reads in-bounds
        const int offd = hasd ? NW * NC : 0;
        float lc0 = base[d], lc1 = base[d + 8], lc2 = h3 ? base[d + 16] : 0.f;
        float lr0 = base[offr + d], lr1 = base[offr + d + 8], lr2 = h3 ? base[offr + d + 16] : 0.f;
        float ld0 = base[offd + d], ld1 = base[offd + d + 8], ld2 = h3 ? base[offd + d + 16] : 0.f;

        // three LSEs via shuffle trees (same op sequence as lse8 -> bit-exact)
        float mc = fmaxf(fmaxf(lc0, lc1), h3 ? lc2 : lc0);
        float mr = fmaxf(fmaxf(lr0, lr1), h3 ? lr2 : lr0);
        float md = fmaxf(fmaxf(ld0, ld1), h3 ? ld2 : ld0);
#pragma unroll
        for (int o = 4; o > 0; o >>= 1) {
            mc = fmaxf(mc, __shfl_xor(mc, o, 8));
            mr = fmaxf(mr, __shfl_xor(mr, o, 8));
            md = fmaxf(md, __shfl_xor(md, o, 8));
        }
        float sc = expf(lc0 - mc) + expf(lc1 - mc) + (h3 ? expf(lc2 - mc) : 0.f);
        float sr = expf(lr0 - mr) + expf(lr1 - mr) + (h3 ? expf(lr2 - mr) : 0.f);
        float sd = expf(ld0 - md) + expf(ld1 - md) + (h3 ? expf(ld2 - md) : 0.f);
#pragma unroll
        for (int o = 4; o > 0; o >>= 1) {
            sc += __shfl_xor(sc, o, 8);
            sr += __shfl_xor(sr, o, 8);
            sd += __shfl_xor(sd, o, 8);
        }
        const float lse_c = mc + logf(sc);
        const float lse_r = mr + logf(sr);
        const float lse_d = md + logf(sd);

        float s0 = lc0 - lse_c, s1 = lc1 - lse_c, s2 = lc2 - lse_c;
        float p0 = expf(s0), p1 = expf(s1), p2 = h3 ? expf(s2) : 0.f;
        float negH = p0 * s0 + p1 * s1 + p2 * s2;
        float dotr = p0 * lr0 + p1 * lr1 + p2 * lr2;
        float dotd = p0 * ld0 + p1 * ld1 + p2 * ld2;
#pragma unroll
        for (int o = 4; o > 0; o >>= 1) {
            negH += __shfl_xor(negH, o, 8);
            dotr += __shfl_xor(dotr, o, 8);
            dotd += __shfl_xor(dotd, o, 8);
        }
        if (d == 0) {
            lsem[p] = lse_c;
            float kl = 0.f;
            if (hasd) kl += negH + lse_d - dotd;
            if (hasr) kl += negH + lse_r - dotr;
            klb[p] = kl;
            int lo = 0, hi = NLAD;
            while (lo < hi) { int mid = (lo + hi) >> 1; if (kl > lad[mid]) lo = mid + 1; else hi = mid; }
            atomicAdd(&lh[lo], 1u);
        }
    }
    __syncthreads();
    if (tid < NLAD + 1 && lh[tid])
        atomicAdd(&hist[(blockIdx.x & (NREP - 1)) * HSTRIDE + tid], lh[tid]);
}

// ---------------------------------------------------------------------------
// Stage 6a: eps (from replica histogram, compile-time ladder) + validity +
// compaction.
// ---------------------------------------------------------------------------
__global__ __launch_bounds__(256) void valid_kernel(const float* __restrict__ klb,
                                                    const float* __restrict__ dist,
                                                    const unsigned int* __restrict__ hist,
                                                    unsigned int* __restrict__ cnts,
                                                    unsigned int* __restrict__ list) {
    __shared__ unsigned int tot[NLAD + 1];
    __shared__ float epsS;
    const int tid = threadIdx.x;
    if (tid < NLAD + 1) {
        unsigned int s = 0;
        for (int r = 0; r < NREP; ++r) s += hist[r * HSTRIDE + tid];
        tot[tid] = s;
    }
    __syncthreads();
    if (tid == 0) {
        unsigned int sufs[NLAD + 2];
        sufs[NLAD + 1] = 0u;
        for (int q = NLAD; q >= 0; --q) sufs[q] = sufs[q + 1] + tot[q];
        int K = 0;
        while (K < NLAD - 1 && (float)sufs[K + 1] > 2621.44f) K++;
        epsS = LADC.v[K];
    }
    __syncthreads();
    const float eps = epsS;

    const int b = blockIdx.z;
    const int i = blockIdx.y * TS + (tid >> 4);
    const int j = blockIdx.x * TS + (tid & 15);
    const float* klp = klb + (size_t)b * NH * NW;
    const float* dp = dist + (size_t)b * NH * NW;

    bool pb = false;
    for (int di = -1; di <= 1; ++di) {
        int ii = i + di; if (ii < 0 || ii >= NH) continue;
        for (int dj = -1; dj <= 1; ++dj) {
            int jj = j + dj; if (jj < 0 || jj >= NW) continue;
            if (klp[(size_t)ii * NW + jj] > eps) pb = true;
        }
    }

    const int dxs[9] = {1, -1, 0, 0, -1, 1, -1, 1, 0};
    const int dys[9] = {0, 0, -1, 1, 1, 1, -1, -1, 0};
    float best = MAXDIS; int gidx = 0;
#pragma unroll
    for (int k = 0; k < 9; ++k) {
        int ii = i + dxs[k], jj = j + dys[k];
        float v = (ii >= 0 && ii < NH && jj >= 0 && jj < NW) ? dp[(size_t)ii * NW + jj] : MAXDIS;
        if (k == 0) { best = v; gidx = 0; }
        else if (v < best) { best = v; gidx = k; }
    }
    bool valid = pb && (gidx != 8);

    const int pix = (b * NH + i) * NW + j;
    const int lane = tid & 63;
    unsigned long long mk = __ballot(valid);
    int cnt = __popcll(mk);
    int flatw = (((blockIdx.z * gridDim.y + blockIdx.y) * gridDim.x + blockIdx.x) << 2) | (tid >> 6);
    int seg = flatw & (NSEG - 1);
    unsigned int base = 0u;
    if (lane == 0 && cnt) base = atomicAdd(&cnts[seg], (unsigned int)cnt);
    base = (unsigned int)__shfl((int)base, 0, 64);
    if (valid) {
        unsigned int off = base + (unsigned int)__popcll(mk & ((1ull << lane) - 1ull));
        if (off < SEGCAP)
            list[seg * SEGCAP + off] = (unsigned int)pix | ((unsigned int)gidx << 20);
    }
}

// ---------------------------------------------------------------------------
// Stage 6b: CE over valid pixels, 8 lanes per pixel, PLUS in-block LDS tree
// reduce -> one partial per block (2048 total).
// ---------------------------------------------------------------------------
__global__ __launch_bounds__(256) void dirce_kernel(const float* __restrict__ logits,
                                                    const float* __restrict__ lsem,
                                                    const float* __restrict__ dist,
                                                    const unsigned int* __restrict__ cnts,
                                                    const unsigned int* __restrict__ list,
                                                    float* __restrict__ partials) {
    __shared__ float rs[256];
    const int tid = threadIdx.x;
    const int t = blockIdx.x * 256 + tid;
    const int e = t >> 3;                       // entry slot
    const int d = t & 7;                        // neighbor lane
    const int s = e >> 9;                       // segment (SEGCAP=512)
    const int k = e & (SEGCAP - 1);
    unsigned int cs = cnts[s];
    float myce = 0.f;
    if ((unsigned int)k < min(cs, (unsigned int)SEGCAP)) {
        unsigned int w = list[s * SEGCAP + k];
        const int pix = (int)(w & (NPIX - 1));
        const int gidx = (int)(w >> 20);
        const int j = pix & (NW - 1);
        const int i = (pix >> 9) & (NH - 1);

        const unsigned int DXP = (2u<<0)|(0u<<2)|(1u<<4)|(1u<<6)|(0u<<8)|(2u<<10)|(0u<<12)|(2u<<14);
        const unsigned int DYP = (1u<<0)|(1u<<2)|(0u<<4)|(2u<<6)|(2u<<8)|(2u<<10)|(0u<<12)|(0u<<14);
        const int dx = (int)((DXP >> (2 * d)) & 3u) - 1;
        const int dy = (int)((DYP >> (2 * d)) & 3u) - 1;
        const int ii = i + dx, jj = j + dy;
        const bool inb = (ii >= 0 && ii < NH && jj >= 0 && jj < NW);

        const float lse_c = lsem[pix];
        const float* lcp = logits + (size_t)pix * NC;
        float lc[NC];
        float sumlc = 0.f;
#pragma unroll
        for (int c = 0; c < NC; ++c) { lc[c] = lcp[c]; sumlc += lc[c]; }

        float klm;
        if (inb) {
            const int npix = pix + dx * NW + dy;
            const float lse_n = lsem[npix];
            const float* lnp = logits + (size_t)npix * NC;
            float negH = 0.f, dot = 0.f;
#pragma unroll
            for (int c = 0; c < NC; ++c) {
                float sv = lnp[c] - lse_n;
                float p = expf(sv);
                negH += p * sv;
                dot += p * lc[c];
            }
            klm = negH + lse_c - dot;
        } else {
            klm = -logf(19.f) + lse_c - sumlc / 19.f;
        }

        float m2 = klm;
#pragma unroll
        for (int o = 4; o > 0; o >>= 1) m2 = fmaxf(m2, __shfl_xor(m2, o, 8));
        float ex = expf(klm - m2);
        float s2 = ex;
#pragma unroll
        for (int o = 4; o > 0; o >>= 1) s2 += __shfl_xor(s2, o, 8);
        float lse = m2 + logf(s2);
        float lp = klm - lse;
        float slp = lp;
#pragma unroll
        for (int o = 4; o > 0; o >>= 1) slp += __shfl_xor(slp, o, 8);
        float kg = (d == gidx) ? lp : 0.f;
#pragma unroll
        for (int o = 4; o > 0; o >>= 1) kg += __shfl_xor(kg, o, 8);

        if (d == 0) {
            float ce = -(0.2f / 8.f) * slp - 0.8f * kg;
            float wgt = fminf(dist[pix], 20.f) / 20.f;
            myce = ce * wgt;
        }
    }
    rs[tid] = myce;
    __syncthreads();
    for (int q = 128; q > 0; q >>= 1) {
        if (tid < q) rs[tid] += rs[tid + q];
        __syncthreads();
    }
    if (tid == 0) partials[blockIdx.x] = rs[0];
}

// ---------------------------------------------------------------------------
// Stage 7: reduce 2048 block partials + valid count -> loss.
// ---------------------------------------------------------------------------
__global__ __launch_bounds__(256) void final_kernel(const float* __restrict__ partials,
                                                    const unsigned int* __restrict__ cnts,
                                                    float* __restrict__ out) {
    __shared__ float r[256];
    const int tid = threadIdx.x;
    float s = 0.f;
#pragma unroll
    for (int q = 0; q < NDCB / 256; ++q) s += partials[tid + q * 256];
    r[tid] = s;
    __syncthreads();
    for (int q = 128; q > 0; q >>= 1) {
        if (tid < q) r[tid] += r[tid + q];
        __syncthreads();
    }
    if (tid == 0) {
        unsigned int vf = 0;
        for (int q = 0; q < NSEG; ++q) vf += cnts[q];
        out[0] = r[0] / fmaxf((float)vf, 1.f);
    }
}

extern "C" void kernel_launch(void* const* d_in, const int* in_sizes, int n_in,
                              void* d_out, int out_size, void* d_ws, size_t ws_size,
                              hipStream_t stream) {
    const float* logits = (const float*)d_in[0];
    const int* target = (const int*)d_in[1];
    float* out = (float*)d_out;

    float* fws = (float*)d_ws;
    float* distb = fws;                         // NPIX floats
    float* klb = fws + NPIX;                    // NPIX floats
    float* lsem = fws + 2 * (size_t)NPIX;       // NPIX floats
    unsigned int* hist = (unsigned int*)(fws + 3 * (size_t)NPIX);   // NREP*HSTRIDE
    unsigned int* cnts = hist + NREP * HSTRIDE;                     // NSEG
    unsigned int* list = cnts + NSEG;                               // NSEG*SEGCAP
    float* partials = (float*)(list + NSEG * SEGCAP);               // NDCB
    unsigned int* maskw = (unsigned int*)(partials + NDCB);         // NB*NWRD*NW

    // bound block 0 zeroes hist+cnts; stream order guards all consumers
    bound_kernel<<<NB * NWRD * NW / 64, 64, 0, stream>>>(target, maskw, hist);
    vdistrow_kernel<<<NB * NH, 512, 0, stream>>>(maskw, distb);

    klf_kernel<<<NPIX / (32 * KITER), 256, 0, stream>>>(logits, lsem, klb, hist);

    dim3 tiles(NW / TS, NH / TS, NB);
    valid_kernel<<<tiles, 256, 0, stream>>>(klb, distb, hist, cnts, list);
    dirce_kernel<<<NDCB, 256, 0, stream>>>(logits, lsem, distb, cnts, list, partials);
    final_kernel<<<1, 256, 0, stream>>>(partials, cnts, out);
}

// Round 15
// 121.494 us; speedup vs baseline: 1.5803x; 1.1931x over previous
//
#include <hip/hip_runtime.h>
#include <math.h>

#define NB 4
#define NH 512
#define NW 512
#define NC 19
#define NPIX (NB*NH*NW)
#define TS 16
#define NLAD 128
#define INF6 1.0e6f
#define MAXDIS 1.0e5f
#define NWRD 16          // 512 rows / 32 bits
#define NREP 8           // histogram replicas
#define HSTRIDE 132      // padded per-replica stride (129 bins)
#define NSEG 128         // compaction segments
#define SEGCAP 512       // entries per segment (expected max ~250)
#define NDCB (NSEG*SEGCAP*8/256)      // dirce blocks = 2048
#define NZERO (NREP*HSTRIDE + NSEG)   // hist + cnts words zeroed by bound blk 0

// Compile-time eps ladder: bit-exact IEEE float chain (e = 1e-5f; e *= 1.2f).
struct Lad { float v[NLAD]; };
static constexpr Lad make_lad() {
    Lad t{};
    float e = 1e-5f;
    for (int k = 0; k < NLAD; ++k) { t.v[k] = e; e *= 1.2f; }
    return t;
}
__constant__ Lad LADC = make_lad();

// 19-float run as 5 overlapping float4s (4B alignment suffices on gfx950;
// proven by rounds 3-4 which float4-cast logits at pixel granularity).
__device__ __forceinline__ void load19(const float* __restrict__ base, float (&v)[NC]) {
    float4 q0 = *reinterpret_cast<const float4*>(base);
    float4 q1 = *reinterpret_cast<const float4*>(base + 4);
    float4 q2 = *reinterpret_cast<const float4*>(base + 8);
    float4 q3 = *reinterpret_cast<const float4*>(base + 12);
    float4 q4 = *reinterpret_cast<const float4*>(base + 15);
    v[0]=q0.x; v[1]=q0.y; v[2]=q0.z; v[3]=q0.w;
    v[4]=q1.x; v[5]=q1.y; v[6]=q1.z; v[7]=q1.w;
    v[8]=q2.x; v[9]=q2.y; v[10]=q2.z; v[11]=q2.w;
    v[12]=q3.x; v[13]=q3.y; v[14]=q3.z; v[15]=q3.w;
    v[16]=q4.y; v[17]=q4.z; v[18]=q4.w;
}

// ---------------------------------------------------------------------------
// Stage 1a: boundary bitmasks. One thread per (b, word, column).
// Block 0 zeroes hist+cnts (stream order guards all consumers).
// ---------------------------------------------------------------------------
__global__ __launch_bounds__(64) void bound_kernel(const int* __restrict__ tgt,
                                                   unsigned int* __restrict__ maskw,
                                                   unsigned int* __restrict__ zbuf) {
    int cidx = blockIdx.x * 64 + threadIdx.x;           // [b][w][j], 32768 total
    if (blockIdx.x == 0) {
        for (int k = threadIdx.x; k < NZERO; k += 64) zbuf[k] = 0u;
    }
    int j = cidx & (NW - 1);
    int w = (cidx >> 9) & (NWRD - 1);
    int b = cidx >> 13;
    const int* t = tgt + (size_t)b * NH * NW;
    unsigned int mask = 0u;
    int i0 = w * 32;
    int cur = t[(size_t)i0 * NW + j];
    for (int k = 0; k < 32; ++k) {
        int i = i0 + k;
        int nxt = (i + 1 < NH) ? t[(size_t)(i + 1) * NW + j] : cur;
        bool bnd = (cur == 255);
        if (i + 1 < NH && nxt != cur) bnd = true;
        if (j + 1 < NW && t[(size_t)i * NW + j + 1] != cur) bnd = true;
        if (bnd) mask |= (1u << k);
        cur = nxt;
    }
    maskw[cidx] = mask;
}

// ---------------------------------------------------------------------------
// Stage 1b+2 fused: block per row; batch mask set in LDS; nearest-set-bit ->
// G^2 -> row min-plus transform -> final dist.
// ---------------------------------------------------------------------------
__global__ __launch_bounds__(512) void vdistrow_kernel(const unsigned int* __restrict__ maskw,
                                                       float* __restrict__ dist) {
    __shared__ unsigned int smw[NWRD][NW];   // 32 KB: all masks of this batch
    __shared__ float s[NW];
    __shared__ unsigned int anyw[8];
    const int tid = threadIdx.x;             // = column j
    const int row = blockIdx.x;              // b*NH + i
    const int b = row >> 9;
    const int i = row & (NH - 1);
    const unsigned int* mcol = maskw + (size_t)b * NWRD * NW;
    unsigned int acc = 0u;
#pragma unroll
    for (int w = 0; w < NWRD; ++w) {
        unsigned int v = mcol[w * NW + tid];
        smw[w][tid] = v;
        acc |= v;
    }
    unsigned long long bal = __ballot(acc != 0u);
    if ((tid & 63) == 0) anyw[tid >> 6] = (bal != 0ull) ? 1u : 0u;

    const int wi = i >> 5, bi = i & 31;
    int down = 1 << 20;
    unsigned int m = smw[wi][tid] & ((2u << bi) - 1u);   // bits 0..bi
    if (m) down = bi - (31 - __clz(m));
    else {
        for (int w = wi - 1; w >= 0; --w) {
            unsigned int mm = smw[w][tid];
            if (mm) { down = bi + 32 * (wi - w) - (31 - __clz(mm)); break; }
        }
    }
    int up = 1 << 20;
    unsigned int mu = smw[wi][tid] & ~((1u << bi) - 1u); // bits bi..31
    if (mu) up = (__ffs(mu) - 1) - bi;
    else {
        for (int w = wi + 1; w < NWRD; ++w) {
            unsigned int mm = smw[w][tid];
            if (mm) { up = 32 * (w - wi) + (__ffs(mm) - 1) - bi; break; }
        }
    }
    int gi = min(down, up);
    float G = (gi >= (1 << 20)) ? INF6 : (float)gi;
    s[tid] = G * G;
    __syncthreads();
    bool has = (anyw[0] | anyw[1] | anyw[2] | anyw[3] |
                anyw[4] | anyw[5] | anyw[6] | anyw[7]) != 0u;
    float best = s[tid];
    for (int r = 1; r < NW; ++r) {
        float rr = (float)(r * r);
        if (rr >= best) break;
        int jl = tid - r, jr = tid + r;
        if (jl >= 0) best = fminf(best, s[jl] + rr);
        if (jr < NW) best = fminf(best, s[jr] + rr);
    }
    dist[(size_t)row * NW + tid] = has ? fmaxf(sqrtf(best) - 1.f, 0.f) : 0.f;
}

// ---------------------------------------------------------------------------
// Stage 3a: per-pixel LSE map, one thread per pixel, 5x float4 loads.
// Bit-identical formula/order to the passing rounds (sequential c=0..18).
// ---------------------------------------------------------------------------
__global__ __launch_bounds__(256) void lse4_kernel(const float* __restrict__ logits,
                                                   float* __restrict__ lsem) {
    const int p = blockIdx.x * 256 + threadIdx.x;
    float v[NC];
    load19(logits + (size_t)p * NC, v);
    float mx = v[0];
#pragma unroll
    for (int c = 1; c < NC; ++c) mx = fmaxf(mx, v[c]);
    float se = 0.f;
#pragma unroll
    for (int c = 0; c < NC; ++c) se += expf(v[c] - mx);
    lsem[p] = mx + logf(se);
}

// ---------------------------------------------------------------------------
// Stage 3b: kl map + fused histogram. One thread per pixel; lc/lr/ld each
// as 5 float4 loads (15 load instrs vs 57 scalar -> ~4x fewer L1
// transactions); LSEs from lsem (each computed once). Accumulation order
// identical to rounds 4-12 (absmax 0).
// ---------------------------------------------------------------------------
__global__ __launch_bounds__(256) void kl4_kernel(const float* __restrict__ logits,
                                                  const float* __restrict__ lsem,
                                                  float* __restrict__ klb,
                                                  unsigned int* __restrict__ hist) {
    __shared__ float lad[NLAD];
    __shared__ unsigned int lh[NLAD + 1];
    const int tid = threadIdx.x;
    if (tid < NLAD) lad[tid] = LADC.v[tid];
    if (tid < NLAD + 1) lh[tid] = 0u;
    __syncthreads();

    const int p = blockIdx.x * 256 + tid;
    const int j = p & (NW - 1);
    const int i = (p >> 9) & (NH - 1);
    const bool hasr = (j < NW - 1), hasd = (i < NH - 1);
    const float lse_c = lsem[p];
    const float lse_r = hasr ? lsem[p + 1] : 0.f;
    const float lse_d = hasd ? lsem[p + NW] : 0.f;
    const float* base = logits + (size_t)p * NC;
    const int offr = hasr ? NC : 0;            // clamp keeps reads in-bounds
    const int offd = hasd ? NW * NC : 0;

    float lc[NC];
    load19(base, lc);
    float pc[NC];
    float negH = 0.f;
#pragma unroll
    for (int c = 0; c < NC; ++c) {
        float s = lc[c] - lse_c;
        float e = expf(s);
        pc[c] = e;
        negH += e * s;
    }
    float lr[NC];
    load19(base + offr, lr);
    float dotr = 0.f;
#pragma unroll
    for (int c = 0; c < NC; ++c) dotr += pc[c] * lr[c];
    float ld[NC];
    load19(base + offd, ld);
    float dotd = 0.f;
#pragma unroll
    for (int c = 0; c < NC; ++c) dotd += pc[c] * ld[c];

    float kl = 0.f;
    if (hasd) kl += negH + lse_d - dotd;
    if (hasr) kl += negH + lse_r - dotr;
    klb[p] = kl;

    int lo = 0, hi = NLAD;
    while (lo < hi) { int mid = (lo + hi) >> 1; if (kl > lad[mid]) lo = mid + 1; else hi = mid; }
    atomicAdd(&lh[lo], 1u);
    __syncthreads();
    if (tid < NLAD + 1 && lh[tid])
        atomicAdd(&hist[(blockIdx.x & (NREP - 1)) * HSTRIDE + tid], lh[tid]);
}

// ---------------------------------------------------------------------------
// Stage 6a: eps (from replica histogram, compile-time ladder) + validity +
// compaction.
// ---------------------------------------------------------------------------
__global__ __launch_bounds__(256) void valid_kernel(const float* __restrict__ klb,
                                                    const float* __restrict__ dist,
                                                    const unsigned int* __restrict__ hist,
                                                    unsigned int* __restrict__ cnts,
                                                    unsigned int* __restrict__ list) {
    __shared__ unsigned int tot[NLAD + 1];
    __shared__ float epsS;
    const int tid = threadIdx.x;
    if (tid < NLAD + 1) {
        unsigned int s = 0;
        for (int r = 0; r < NREP; ++r) s += hist[r * HSTRIDE + tid];
        tot[tid] = s;
    }
    __syncthreads();
    if (tid == 0) {
        unsigned int sufs[NLAD + 2];
        sufs[NLAD + 1] = 0u;
        for (int q = NLAD; q >= 0; --q) sufs[q] = sufs[q + 1] + tot[q];
        int K = 0;
        while (K < NLAD - 1 && (float)sufs[K + 1] > 2621.44f) K++;
        epsS = LADC.v[K];
    }
    __syncthreads();
    const float eps = epsS;

    const int b = blockIdx.z;
    const int i = blockIdx.y * TS + (tid >> 4);
    const int j = blockIdx.x * TS + (tid & 15);
    const float* klp = klb + (size_t)b * NH * NW;
    const float* dp = dist + (size_t)b * NH * NW;

    bool pb = false;
    for (int di = -1; di <= 1; ++di) {
        int ii = i + di; if (ii < 0 || ii >= NH) continue;
        for (int dj = -1; dj <= 1; ++dj) {
            int jj = j + dj; if (jj < 0 || jj >= NW) continue;
            if (klp[(size_t)ii * NW + jj] > eps) pb = true;
        }
    }

    const int dxs[9] = {1, -1, 0, 0, -1, 1, -1, 1, 0};
    const int dys[9] = {0, 0, -1, 1, 1, 1, -1, -1, 0};
    float best = MAXDIS; int gidx = 0;
#pragma unroll
    for (int k = 0; k < 9; ++k) {
        int ii = i + dxs[k], jj = j + dys[k];
        float v = (ii >= 0 && ii < NH && jj >= 0 && jj < NW) ? dp[(size_t)ii * NW + jj] : MAXDIS;
        if (k == 0) { best = v; gidx = 0; }
        else if (v < best) { best = v; gidx = k; }
    }
    bool valid = pb && (gidx != 8);

    const int pix = (b * NH + i) * NW + j;
    const int lane = tid & 63;
    unsigned long long mk = __ballot(valid);
    int cnt = __popcll(mk);
    int flatw = (((blockIdx.z * gridDim.y + blockIdx.y) * gridDim.x + blockIdx.x) << 2) | (tid >> 6);
    int seg = flatw & (NSEG - 1);
    unsigned int base = 0u;
    if (lane == 0 && cnt) base = atomicAdd(&cnts[seg], (unsigned int)cnt);
    base = (unsigned int)__shfl((int)base, 0, 64);
    if (valid) {
        unsigned int off = base + (unsigned int)__popcll(mk & ((1ull << lane) - 1ull));
        if (off < SEGCAP)
            list[seg * SEGCAP + off] = (unsigned int)pix | ((unsigned int)gidx << 20);
    }
}

// ---------------------------------------------------------------------------
// Stage 6b: CE over valid pixels, 8 lanes per pixel, PLUS in-block LDS tree
// reduce -> one partial per block (2048 total).
// ---------------------------------------------------------------------------
__global__ __launch_bounds__(256) void dirce_kernel(const float* __restrict__ logits,
                                                    const float* __restrict__ lsem,
                                                    const float* __restrict__ dist,
                                                    const unsigned int* __restrict__ cnts,
                                                    const unsigned int* __restrict__ list,
                                                    float* __restrict__ partials) {
    __shared__ float rs[256];
    const int tid = threadIdx.x;
    const int t = blockIdx.x * 256 + tid;
    const int e = t >> 3;                       // entry slot
    const int d = t & 7;                        // neighbor lane
    const int s = e >> 9;                       // segment (SEGCAP=512)
    const int k = e & (SEGCAP - 1);
    unsigned int cs = cnts[s];
    float myce = 0.f;
    if ((unsigned int)k < min(cs, (unsigned int)SEGCAP)) {
        unsigned int w = list[s * SEGCAP + k];
        const int pix = (int)(w & (NPIX - 1));
        const int gidx = (int)(w >> 20);
        const int j = pix & (NW - 1);
        const int i = (pix >> 9) & (NH - 1);

        const unsigned int DXP = (2u<<0)|(0u<<2)|(1u<<4)|(1u<<6)|(0u<<8)|(2u<<10)|(0u<<12)|(2u<<14);
        const unsigned int DYP = (1u<<0)|(1u<<2)|(0u<<4)|(2u<<6)|(2u<<8)|(2u<<10)|(0u<<12)|(0u<<14);
        const int dx = (int)((DXP >> (2 * d)) & 3u) - 1;
        const int dy = (int)((DYP >> (2 * d)) & 3u) - 1;
        const int ii = i + dx, jj = j + dy;
        const bool inb = (ii >= 0 && ii < NH && jj >= 0 && jj < NW);

        const float lse_c = lsem[pix];
        const float* lcp = logits + (size_t)pix * NC;
        float lc[NC];
        float sumlc = 0.f;
#pragma unroll
        for (int c = 0; c < NC; ++c) { lc[c] = lcp[c]; sumlc += lc[c]; }

        float klm;
        if (inb) {
            const int npix = pix + dx * NW + dy;
            const float lse_n = lsem[npix];
            const float* lnp = logits + (size_t)npix * NC;
            float negH = 0.f, dot = 0.f;
#pragma unroll
            for (int c = 0; c < NC; ++c) {
                float sv = lnp[c] - lse_n;
                float p = expf(sv);
                negH += p * sv;
                dot += p * lc[c];
            }
            klm = negH + lse_c - dot;
        } else {
            klm = -logf(19.f) + lse_c - sumlc / 19.f;
        }

        float m2 = klm;
#pragma unroll
        for (int o = 4; o > 0; o >>= 1) m2 = fmaxf(m2, __shfl_xor(m2, o, 8));
        float ex = expf(klm - m2);
        float s2 = ex;
#pragma unroll
        for (int o = 4; o > 0; o >>= 1) s2 += __shfl_xor(s2, o, 8);
        float lse = m2 + logf(s2);
        float lp = klm - lse;
        float slp = lp;
#pragma unroll
        for (int o = 4; o > 0; o >>= 1) slp += __shfl_xor(slp, o, 8);
        float kg = (d == gidx) ? lp : 0.f;
#pragma unroll
        for (int o = 4; o > 0; o >>= 1) kg += __shfl_xor(kg, o, 8);

        if (d == 0) {
            float ce = -(0.2f / 8.f) * slp - 0.8f * kg;
            float wgt = fminf(dist[pix], 20.f) / 20.f;
            myce = ce * wgt;
        }
    }
    rs[tid] = myce;
    __syncthreads();
    for (int q = 128; q > 0; q >>= 1) {
        if (tid < q) rs[tid] += rs[tid + q];
        __syncthreads();
    }
    if (tid == 0) partials[blockIdx.x] = rs[0];
}

// ---------------------------------------------------------------------------
// Stage 7: reduce 2048 block partials + valid count -> loss.
// ---------------------------------------------------------------------------
__global__ __launch_bounds__(256) void final_kernel(const float* __restrict__ partials,
                                                    const unsigned int* __restrict__ cnts,
                                                    float* __restrict__ out) {
    __shared__ float r[256];
    const int tid = threadIdx.x;
    float s = 0.f;
#pragma unroll
    for (int q = 0; q < NDCB / 256; ++q) s += partials[tid + q * 256];
    r[tid] = s;
    __syncthreads();
    for (int q = 128; q > 0; q >>= 1) {
        if (tid < q) r[tid] += r[tid + q];
        __syncthreads();
    }
    if (tid == 0) {
        unsigned int vf = 0;
        for (int q = 0; q < NSEG; ++q) vf += cnts[q];
        out[0] = r[0] / fmaxf((float)vf, 1.f);
    }
}

extern "C" void kernel_launch(void* const* d_in, const int* in_sizes, int n_in,
                              void* d_out, int out_size, void* d_ws, size_t ws_size,
                              hipStream_t stream) {
    const float* logits = (const float*)d_in[0];
    const int* target = (const int*)d_in[1];
    float* out = (float*)d_out;

    float* fws = (float*)d_ws;
    float* distb = fws;                         // NPIX floats
    float* klb = fws + NPIX;                    // NPIX floats
    float* lsem = fws + 2 * (size_t)NPIX;       // NPIX floats
    unsigned int* hist = (unsigned int*)(fws + 3 * (size_t)NPIX);   // NREP*HSTRIDE
    unsigned int* cnts = hist + NREP * HSTRIDE;                     // NSEG
    unsigned int* list = cnts + NSEG;                               // NSEG*SEGCAP
    float* partials = (float*)(list + NSEG * SEGCAP);               // NDCB
    unsigned int* maskw = (unsigned int*)(partials + NDCB);         // NB*NWRD*NW

    // bound block 0 zeroes hist+cnts; stream order guards all consumers
    bound_kernel<<<NB * NWRD * NW / 64, 64, 0, stream>>>(target, maskw, hist);
    vdistrow_kernel<<<NB * NH, 512, 0, stream>>>(maskw, distb);

    lse4_kernel<<<NPIX / 256, 256, 0, stream>>>(logits, lsem);
    kl4_kernel<<<NPIX / 256, 256, 0, stream>>>(logits, lsem, klb, hist);

    dim3 tiles(NW / TS, NH / TS, NB);
    valid_kernel<<<tiles, 256, 0, stream>>>(klb, distb, hist, cnts, list);
    dirce_kernel<<<NDCB, 256, 0, stream>>>(logits, lsem, distb, cnts, list, partials);
    final_kernel<<<1, 256, 0, stream>>>(partials, cnts, out);
}